// Round 6
// baseline (360.816 us; speedup 1.0000x reference)
//
#include <hip/hip_runtime.h>

typedef __attribute__((ext_vector_type(4))) float f32x4;
typedef __attribute__((ext_vector_type(8))) short bf16x8;

#define BM 256
#define BN 256
#define BK 64
// halftile = K-half of a K-tile: 256 rows x 32 cols bf16 = 16 KiB = 8192 ushorts

static __device__ __forceinline__ ushort f2b(float f) {
    uint u = __float_as_uint(f);
    uint r = (u + 0x7fffu + ((u >> 16) & 1u)) >> 16;
    return (ushort)r;
}
static __device__ __forceinline__ float b2f(ushort h) {
    return __uint_as_float(((uint)h) << 16);
}

// ---------------- fp32 -> bf16 convert (vectorized, grid-stride) -------------
__global__ __launch_bounds__(256) void f2b_kernel(const float* __restrict__ in,
                                                  ushort* __restrict__ out, int n4) {
    int i = blockIdx.x * blockDim.x + threadIdx.x;
    int stride = gridDim.x * blockDim.x;
    for (; i < n4; i += stride) {
        float4 v = ((const float4*)in)[i];
        ushort4 o;
        o.x = f2b(v.x); o.y = f2b(v.y); o.z = f2b(v.z); o.w = f2b(v.w);
        ((ushort4*)out)[i] = o;
    }
}

// ---------------- bf16 GEMM, C = A * B^T, 256x256 tile, BK=64 --------------
// K-split halftiles (256x32 each), double-buffered per K-tile; 4 phases per
// K-tile, each {ds_read cluster; stage 1 halftile; SGB; barrier; lgkm0; SGB;
// setprio; 16 MFMA; setprio; SGB; barrier}. Counted vmcnt(4) at P2/P4 only.
// LDS swizzle g: byte ^= ((row&7)<<4); global_load_lds writes LINEAR dest,
// global SOURCE pre-inverse-swizzled (rule #21).
__device__ __forceinline__ void stage_half(
    const ushort* __restrict__ G, ushort* Ls, int kt, int h, int rc0,
    int r0, int c0, int r1, int c1, int w) {
    // slot for K-tile kt, K-half h
    ushort* base = Ls + (((kt & 1) * 2 + h) * 8192);
    ushort* l0 = base + (w << 6) * 8;            // instr 0: bytes [w*1024 ..)
    ushort* l1 = base + (512 + (w << 6)) * 8;    // instr 1: bytes [8192+w*1024 ..)
    int kcol = kt * BK + h * 32;
    const ushort* g0 = G + (size_t)(rc0 + r0) * 1024 + kcol + c0 * 8;
    const ushort* g1 = G + (size_t)(rc0 + r1) * 1024 + kcol + c1 * 8;
    __builtin_amdgcn_global_load_lds((const __attribute__((address_space(1))) void*)g0,
                                     (__attribute__((address_space(3))) void*)l0, 16, 0, 0);
    __builtin_amdgcn_global_load_lds((const __attribute__((address_space(1))) void*)g1,
                                     (__attribute__((address_space(3))) void*)l1, 16, 0, 0);
}

__global__ __launch_bounds__(512, 2) void gemm_bt4(const ushort* __restrict__ A,
                                                   const ushort* __restrict__ Bw,
                                                   ushort* __restrict__ C) {
    __shared__ ushort As[4 * 8192];  // 2 bufs x 2 K-halves, 64 KiB
    __shared__ ushort Bs[4 * 8192];  // 64 KiB
    const int CTN = 4;  // 1024 / BN

    // T1: XCD-chunked swizzle (nwg = 512, divisible by 8)
    int nwg = gridDim.x;
    int cpx = nwg >> 3;
    int bid = blockIdx.x;
    int orig = (bid & 7) * cpx + (bid >> 3);
    int rt = orig / CTN, ct = orig % CTN;
    int row0 = rt * BM, col0 = ct * BN;

    int t = threadIdx.x, l = t & 63, w = t >> 6;
    int wr = w >> 2, wc = w & 3;       // wave grid 2 (M) x 4 (N)
    int lr = l & 15, c16 = l >> 4;

    // staging geometry: invert swizzle for this thread's two 16B chunks
    int r_[2], c_[2];
#pragma unroll
    for (int i = 0; i < 2; ++i) {
        int d = (i * 512 + t) * 16;
        int rr = ((d >> 6) & ~1) | (((d >> 6) ^ (d >> 8)) & 1);
        r_[i] = rr;
        c_[i] = ((d >> 4) & 3) ^ (rr & 3);
    }

    // fragment read bases (byte offsets within one 16 KiB halftile)
    int mask = (lr & 7) << 4;
    int baseA = ((((wr * 128 + lr) << 6) | (c16 << 4)) ^ mask);
    int baseB = ((((wc * 64 + lr) << 6) | (c16 << 4)) ^ mask);

    f32x4 acc[8][4] = {};

    const int NT = 16;  // K=1024 / BK
    // prologue: K-tile 0's four halftiles (as-if staged during kt=-1)
    stage_half(A, As, 0, 0, row0, r_[0], c_[0], r_[1], c_[1], w);
    stage_half(Bw, Bs, 0, 0, col0, r_[0], c_[0], r_[1], c_[1], w);
    stage_half(A, As, 0, 1, row0, r_[0], c_[0], r_[1], c_[1], w);
    stage_half(Bw, Bs, 0, 1, col0, r_[0], c_[0], r_[1], c_[1], w);
    asm volatile("s_waitcnt vmcnt(4)" ::: "memory");  // A0,B0 landed; A1,B1 fly
    __builtin_amdgcn_s_barrier();

    for (int kt = 0; kt < NT; ++kt) {
        const char* Ab = (const char*)As + (kt & 1) * 32768;
        const char* Bb = (const char*)Bs + (kt & 1) * 32768;
        bf16x8 a[4], b[4];

        // ===== P1: ks=0, m=0..3; stage A0(kt+1) =====
#pragma unroll
        for (int m = 0; m < 4; ++m)
            a[m] = *(const bf16x8*)(Ab + baseA + m * 1024);
#pragma unroll
        for (int n = 0; n < 4; ++n)
            b[n] = *(const bf16x8*)(Bb + baseB + n * 1024);
        if (kt + 1 < NT)
            stage_half(A, As, kt + 1, 0, row0, r_[0], c_[0], r_[1], c_[1], w);
        __builtin_amdgcn_sched_barrier(0);
        __builtin_amdgcn_s_barrier();
        asm volatile("s_waitcnt lgkmcnt(0)" ::: "memory");
        __builtin_amdgcn_sched_barrier(0);
        __builtin_amdgcn_s_setprio(1);
#pragma unroll
        for (int m = 0; m < 4; ++m)
#pragma unroll
            for (int n = 0; n < 4; ++n)
                acc[m][n] = __builtin_amdgcn_mfma_f32_16x16x32_bf16(a[m], b[n], acc[m][n], 0, 0, 0);
        __builtin_amdgcn_s_setprio(0);
        __builtin_amdgcn_sched_barrier(0);
        __builtin_amdgcn_s_barrier();

        // ===== P2: ks=0, m=4..7; stage B0(kt+1); vmcnt checkpoint =====
#pragma unroll
        for (int m = 0; m < 4; ++m)
            a[m] = *(const bf16x8*)(Ab + baseA + (m + 4) * 1024);
        if (kt + 1 < NT)
            stage_half(Bw, Bs, kt + 1, 0, col0, r_[0], c_[0], r_[1], c_[1], w);
        // gate P3's reads: need A1(kt),B1(kt); newer in flight: A0,B0 of kt+1
        if (kt < NT - 1) asm volatile("s_waitcnt vmcnt(4)" ::: "memory");
        else             asm volatile("s_waitcnt vmcnt(0)" ::: "memory");
        __builtin_amdgcn_sched_barrier(0);
        __builtin_amdgcn_s_barrier();
        asm volatile("s_waitcnt lgkmcnt(0)" ::: "memory");
        __builtin_amdgcn_sched_barrier(0);
        __builtin_amdgcn_s_setprio(1);
#pragma unroll
        for (int m = 0; m < 4; ++m)
#pragma unroll
            for (int n = 0; n < 4; ++n)
                acc[m + 4][n] = __builtin_amdgcn_mfma_f32_16x16x32_bf16(a[m], b[n], acc[m + 4][n], 0, 0, 0);
        __builtin_amdgcn_s_setprio(0);
        __builtin_amdgcn_sched_barrier(0);
        __builtin_amdgcn_s_barrier();

        // ===== P3: ks=1, m=0..3; stage A1(kt+1) =====
#pragma unroll
        for (int m = 0; m < 4; ++m)
            a[m] = *(const bf16x8*)(Ab + 16384 + baseA + m * 1024);
#pragma unroll
        for (int n = 0; n < 4; ++n)
            b[n] = *(const bf16x8*)(Bb + 16384 + baseB + n * 1024);
        if (kt + 1 < NT)
            stage_half(A, As, kt + 1, 1, row0, r_[0], c_[0], r_[1], c_[1], w);
        __builtin_amdgcn_sched_barrier(0);
        __builtin_amdgcn_s_barrier();
        asm volatile("s_waitcnt lgkmcnt(0)" ::: "memory");
        __builtin_amdgcn_sched_barrier(0);
        __builtin_amdgcn_s_setprio(1);
#pragma unroll
        for (int m = 0; m < 4; ++m)
#pragma unroll
            for (int n = 0; n < 4; ++n)
                acc[m][n] = __builtin_amdgcn_mfma_f32_16x16x32_bf16(a[m], b[n], acc[m][n], 0, 0, 0);
        __builtin_amdgcn_s_setprio(0);
        __builtin_amdgcn_sched_barrier(0);
        __builtin_amdgcn_s_barrier();

        // ===== P4: ks=1, m=4..7; stage B1(kt+1); vmcnt checkpoint =====
#pragma unroll
        for (int m = 0; m < 4; ++m)
            a[m] = *(const bf16x8*)(Ab + 16384 + baseA + (m + 4) * 1024);
        if (kt + 1 < NT)
            stage_half(Bw, Bs, kt + 1, 1, col0, r_[0], c_[0], r_[1], c_[1], w);
        // gate next kt's P1 reads: need A0,B0 of kt+1; newer: A1,B1 of kt+1
        if (kt + 1 < NT) asm volatile("s_waitcnt vmcnt(4)" ::: "memory");
        __builtin_amdgcn_sched_barrier(0);
        __builtin_amdgcn_s_barrier();
        asm volatile("s_waitcnt lgkmcnt(0)" ::: "memory");
        __builtin_amdgcn_sched_barrier(0);
        __builtin_amdgcn_s_setprio(1);
#pragma unroll
        for (int m = 0; m < 4; ++m)
#pragma unroll
            for (int n = 0; n < 4; ++n)
                acc[m + 4][n] = __builtin_amdgcn_mfma_f32_16x16x32_bf16(a[m], b[n], acc[m + 4][n], 0, 0, 0);
        __builtin_amdgcn_s_setprio(0);
        __builtin_amdgcn_sched_barrier(0);
        __builtin_amdgcn_s_barrier();
    }

    // epilogue: C/D layout col=lane&15, row=(lane>>4)*4+reg
#pragma unroll
    for (int m = 0; m < 8; ++m) {
        int gr = row0 + wr * 128 + m * 16 + c16 * 4;
#pragma unroll
        for (int n = 0; n < 4; ++n) {
            int gc = col0 + wc * 64 + n * 16 + lr;
#pragma unroll
            for (int j = 0; j < 4; ++j)
                C[(size_t)(gr + j) * 1024 + gc] = f2b(acc[m][n][j]);
        }
    }
}

// ---------------- gf[b,e] = mean_n( l2norm(K_pre)[n,e] * V[n,e] ) -----------
__global__ __launch_bounds__(256) void kv_reduce(const ushort* __restrict__ Kp,
                                                 const ushort* __restrict__ Vp,
                                                 float* __restrict__ gf) {
    const int D = 1024, N = 4096;
    int b = blockIdx.y;
    int t = threadIdx.x, l = t & 63, w = t >> 6;
    int r0 = blockIdx.x * 128 + w * 32;  // gridDim.x = 32, 4 waves x 32 rows
    __shared__ float part[4][1024];

    float acc[2][8] = {};
    for (int r = 0; r < 32; ++r) {
        size_t row = (size_t)b * N + r0 + r;
        bf16x8 kv0 = *(const bf16x8*)&Kp[row * D + l * 8];
        bf16x8 kv1 = *(const bf16x8*)&Kp[row * D + l * 8 + 512];
        bf16x8 vv0 = *(const bf16x8*)&Vp[row * D + l * 8];
        bf16x8 vv1 = *(const bf16x8*)&Vp[row * D + l * 8 + 512];
        float kf0[8], kf1[8], ss = 0.f;
#pragma unroll
        for (int j = 0; j < 8; ++j) {
            kf0[j] = b2f((ushort)kv0[j]);
            kf1[j] = b2f((ushort)kv1[j]);
            ss += kf0[j] * kf0[j] + kf1[j] * kf1[j];
        }
#pragma unroll
        for (int off = 32; off; off >>= 1) ss += __shfl_xor(ss, off);
        float inv = 1.0f / fmaxf(sqrtf(ss), 1e-12f);
#pragma unroll
        for (int j = 0; j < 8; ++j) {
            acc[0][j] += kf0[j] * inv * b2f((ushort)vv0[j]);
            acc[1][j] += kf1[j] * inv * b2f((ushort)vv1[j]);
        }
    }
#pragma unroll
    for (int i = 0; i < 2; ++i)
#pragma unroll
        for (int j = 0; j < 8; ++j)
            part[w][l * 8 + i * 512 + j] = acc[i][j];
    __syncthreads();
    const float sc = 1.0f / 4096.0f;
#pragma unroll
    for (int i = 0; i < 4; ++i) {
        int c = t * 4 + i;
        float s = part[0][c] + part[1][c] + part[2][c] + part[3][c];
        atomicAdd(&gf[b * D + c], s * sc);
    }
}

// ---------------- out[row,e] = l2norm(Q_pre)[row,e] * gf[b,e]  (fp32 out) ---
__global__ __launch_bounds__(256) void q_scale(const ushort* __restrict__ Qp,
                                               const float* __restrict__ gf,
                                               float* __restrict__ out) {
    const int D = 1024;
    int row = blockIdx.x * 4 + (threadIdx.x >> 6);
    int l = threadIdx.x & 63;
    int b = row >> 12;  // N = 4096
    const ushort* qr = &Qp[(size_t)row * D];
    float qf[4][4];
    float ss = 0.f;
#pragma unroll
    for (int i = 0; i < 4; ++i) {
        ushort4 q = *(const ushort4*)&qr[l * 4 + i * 256];
        qf[i][0] = b2f(q.x); qf[i][1] = b2f(q.y);
        qf[i][2] = b2f(q.z); qf[i][3] = b2f(q.w);
        ss += qf[i][0] * qf[i][0] + qf[i][1] * qf[i][1] +
              qf[i][2] * qf[i][2] + qf[i][3] * qf[i][3];
    }
#pragma unroll
    for (int off = 32; off; off >>= 1) ss += __shfl_xor(ss, off);
    float inv = 1.0f / fmaxf(sqrtf(ss), 1e-12f);
#pragma unroll
    for (int i = 0; i < 4; ++i) {
        float4 g = *(const float4*)&gf[b * D + l * 4 + i * 256];
        float4 o;
        o.x = qf[i][0] * inv * g.x;
        o.y = qf[i][1] * inv * g.y;
        o.z = qf[i][2] * inv * g.z;
        o.w = qf[i][3] * inv * g.w;
        *(float4*)&out[(size_t)row * D + l * 4 + i * 256] = o;
    }
}

extern "C" void kernel_launch(void* const* d_in, const int* in_sizes, int n_in,
                              void* d_out, int out_size, void* d_ws, size_t ws_size,
                              hipStream_t stream) {
    const float* x  = (const float*)d_in[0];
    const float* Wq = (const float*)d_in[1];
    const float* Wk = (const float*)d_in[2];
    const float* Wv = (const float*)d_in[3];
    float* out = (float*)d_out;

    const int Bb = 8, Nn = 4096, D = 1024;
    const int M = Bb * Nn;  // 32768 rows

    char* ws = (char*)d_ws;
    ushort* xb  = (ushort*)ws;                         // 67108864 B
    ushort* wqb = (ushort*)(ws + 67108864);            // 2097152 B  } contiguous
    ushort* wkb = (ushort*)(ws + 69206016);            // 2097152 B  } (converted
    ushort* wvb = (ushort*)(ws + 71303168);            // 2097152 B  }  in one go)
    ushort* P1  = (ushort*)(ws + 73400320);            // 67108864 B (Q_pre)
    float*  gf  = (float*)(ws + 140509184);            // 32768 B

    // d_out (134.2 MB) doubles as bf16 scratch for K_pre / V until q_scale.
    ushort* Kp = (ushort*)d_out;
    ushort* Vp = Kp + (size_t)M * D;

    hipMemsetAsync(gf, 0, Bb * D * sizeof(float), stream);

    // Wq/Wk/Wv are consecutive inputs of identical size -> but separate
    // allocations; convert each (cheap). x in one big launch.
    f2b_kernel<<<2048, 256, 0, stream>>>(x, xb, (M * D) / 4);
    f2b_kernel<<<256, 256, 0, stream>>>(Wq, wqb, (D * D) / 4);
    f2b_kernel<<<256, 256, 0, stream>>>(Wk, wkb, (D * D) / 4);
    f2b_kernel<<<256, 256, 0, stream>>>(Wv, wvb, (D * D) / 4);

    gemm_bt4<<<512, 512, 0, stream>>>(xb, wkb, Kp);
    gemm_bt4<<<512, 512, 0, stream>>>(xb, wvb, Vp);
    kv_reduce<<<dim3(32, 8), 256, 0, stream>>>(Kp, Vp, gf);
    gemm_bt4<<<512, 512, 0, stream>>>(xb, wqb, P1);
    q_scale<<<M / 4, 256, 0, stream>>>(P1, gf, out);
}

// Round 8
// 335.358 us; speedup vs baseline: 1.0759x; 1.0759x over previous
//
#include <hip/hip_runtime.h>

typedef __attribute__((ext_vector_type(4))) float f32x4;
typedef __attribute__((ext_vector_type(8))) short bf16x8;

#define BM 256
#define BN 256
#define BK 32
// per-matrix per-tile LDS: 256 rows x 32 cols x 2B = 16384 B = 8192 ushorts

static __device__ __forceinline__ ushort f2b(float f) {
    uint u = __float_as_uint(f);
    uint r = (u + 0x7fffu + ((u >> 16) & 1u)) >> 16;
    return (ushort)r;
}
static __device__ __forceinline__ float b2f(ushort h) {
    return __uint_as_float(((uint)h) << 16);
}

// ---------------- fp32 -> bf16 convert (vectorized, grid-stride) -------------
__global__ __launch_bounds__(256) void f2b_kernel(const float* __restrict__ in,
                                                  ushort* __restrict__ out, int n4) {
    int i = blockIdx.x * blockDim.x + threadIdx.x;
    int stride = gridDim.x * blockDim.x;
    for (; i < n4; i += stride) {
        float4 v = ((const float4*)in)[i];
        ushort4 o;
        o.x = f2b(v.x); o.y = f2b(v.y); o.z = f2b(v.z); o.w = f2b(v.w);
        ((ushort4*)out)[i] = o;
    }
}

// ---- three equally-sized fp32 arrays -> one contiguous bf16 output ---------
// grid-stride (R7 bug: single-shot with too few threads left W_k/W_v poison)
__global__ __launch_bounds__(256) void f2b3_kernel(const float* __restrict__ A,
                                                   const float* __restrict__ B,
                                                   const float* __restrict__ C,
                                                   ushort* __restrict__ out, int n4) {
    int i = blockIdx.x * blockDim.x + threadIdx.x;
    int stride = gridDim.x * blockDim.x;
    for (; i < 3 * n4; i += stride) {
        const float* src = (i < n4) ? A : ((i < 2 * n4) ? B : C);
        int j = (i < n4) ? i : ((i < 2 * n4) ? i - n4 : i - 2 * n4);
        float4 v = ((const float4*)src)[j];
        ushort4 o;
        o.x = f2b(v.x); o.y = f2b(v.y); o.z = f2b(v.z); o.w = f2b(v.w);
        ((ushort4*)out)[i] = o;
    }
}

// ---------------- bf16 GEMM, C = A * B^T, 256x256 tile, BK=32 --------------
// R4-proven schedule: ring-4 LDS, stage-ahead 3, 2 pinned phases per K-tile
// (reads split 8/4), counted vmcnt(8/4/0), setprio around MFMA clusters.
// Within-row swizzle: g(r,c16) = r*64 + ((c16 ^ ((r>>2)&3))<<4)  (bytes).
// Read side: 8 disjoint 16B bank-spans per wave read (b128-optimal);
// staging source permutes 16B chunks only INSIDE each 64B row segment ->
// fully coalesced global reads, no L2 line splitting.
__device__ __forceinline__ void stage_mat(
    const ushort* __restrict__ G, ushort* Ls, int tt, int rc0,
    int r0, int c0, int r1, int c1, int w) {
    int buf = tt & 3;
    int k0 = tt * BK;
    ushort* l0 = Ls + buf * 8192 + (w << 6) * 8;
    ushort* l1 = Ls + buf * 8192 + (512 + (w << 6)) * 8;
    const ushort* g0 = G + (size_t)(rc0 + r0) * 1024 + k0 + c0 * 8;
    const ushort* g1 = G + (size_t)(rc0 + r1) * 1024 + k0 + c1 * 8;
    __builtin_amdgcn_global_load_lds((const __attribute__((address_space(1))) void*)g0,
                                     (__attribute__((address_space(3))) void*)l0, 16, 0, 0);
    __builtin_amdgcn_global_load_lds((const __attribute__((address_space(1))) void*)g1,
                                     (__attribute__((address_space(3))) void*)l1, 16, 0, 0);
}

__global__ __launch_bounds__(512, 2) void gemm_bt5(const ushort* __restrict__ A,
                                                   const ushort* __restrict__ Bw,
                                                   ushort* __restrict__ C) {
    __shared__ ushort As[4 * 8192];  // 64 KiB
    __shared__ ushort Bs[4 * 8192];  // 64 KiB
    const int CTN = 4;  // 1024 / BN

    // T1: XCD-chunked swizzle (nwg = 512, divisible by 8)
    int nwg = gridDim.x;
    int cpx = nwg >> 3;
    int bid = blockIdx.x;
    int orig = (bid & 7) * cpx + (bid >> 3);
    int rt = orig / CTN, ct = orig % CTN;
    int row0 = rt * BM, col0 = ct * BN;

    int t = threadIdx.x, l = t & 63, w = t >> 6;
    int wr = w >> 2, wc = w & 3;       // wave grid 2 (M) x 4 (N)
    int lr = l & 15, c16 = l >> 4;

    // staging geometry: invert within-row swizzle for this thread's two chunks
    int r_[2], c_[2];
#pragma unroll
    for (int i = 0; i < 2; ++i) {
        int d16 = i * 512 + t;          // 16B-chunk index within the tile
        int rr = d16 >> 2;
        r_[i] = rr;
        c_[i] = (d16 & 3) ^ ((rr >> 2) & 3);
    }

    // fragment read bases (byte offsets within one 16 KiB tile)
    int sw = (c16 ^ ((lr >> 2) & 3)) << 4;
    int baseA = (((wr * 128 + lr) << 6) | sw);
    int baseB = (((wc * 64 + lr) << 6) | sw);

    f32x4 acc[8][4] = {};

    const int NT = 32;  // K=1024 / BK
    stage_mat(A, As, 0, row0, r_[0], c_[0], r_[1], c_[1], w);
    stage_mat(Bw, Bs, 0, col0, r_[0], c_[0], r_[1], c_[1], w);
    stage_mat(A, As, 1, row0, r_[0], c_[0], r_[1], c_[1], w);
    stage_mat(Bw, Bs, 1, col0, r_[0], c_[0], r_[1], c_[1], w);
    stage_mat(A, As, 2, row0, r_[0], c_[0], r_[1], c_[1], w);
    stage_mat(Bw, Bs, 2, col0, r_[0], c_[0], r_[1], c_[1], w);
    asm volatile("s_waitcnt vmcnt(8)" ::: "memory");  // tile 0 landed
    __builtin_amdgcn_s_barrier();

    for (int tt = 0; tt < NT; ++tt) {
        const char* At = (const char*)As + (tt & 3) * 16384;
        const char* Bt = (const char*)Bs + (tt & 3) * 16384;
        bf16x8 a0[4], a1[4], b[4];

        // ---- phase A: read a[0:4], b[0:4]; stage next A; 16 MFMA ----
#pragma unroll
        for (int m = 0; m < 4; ++m)
            a0[m] = *(const bf16x8*)(At + baseA + m * 1024);
#pragma unroll
        for (int n = 0; n < 4; ++n)
            b[n] = *(const bf16x8*)(Bt + baseB + n * 1024);
        if (tt + 3 < NT)
            stage_mat(A, As, tt + 3, row0, r_[0], c_[0], r_[1], c_[1], w);
        __builtin_amdgcn_sched_barrier(0);
        __builtin_amdgcn_s_barrier();
        asm volatile("s_waitcnt lgkmcnt(0)" ::: "memory");
        __builtin_amdgcn_sched_barrier(0);
        __builtin_amdgcn_s_setprio(1);
#pragma unroll
        for (int m = 0; m < 4; ++m)
#pragma unroll
            for (int n = 0; n < 4; ++n)
                acc[m][n] = __builtin_amdgcn_mfma_f32_16x16x32_bf16(a0[m], b[n], acc[m][n], 0, 0, 0);
        __builtin_amdgcn_s_setprio(0);
        __builtin_amdgcn_sched_barrier(0);
        __builtin_amdgcn_s_barrier();

        // ---- phase B: read a[4:8]; stage next B; vmcnt; 16 MFMA ----
#pragma unroll
        for (int m = 0; m < 4; ++m)
            a1[m] = *(const bf16x8*)(At + baseA + (m + 4) * 1024);
        if (tt + 3 < NT)
            stage_mat(Bw, Bs, tt + 3, col0, r_[0], c_[0], r_[1], c_[1], w);
        // guarantee tile tt+1 landed for next phase A (newer: tiles tt+2,tt+3)
        if (tt <= NT - 4)      asm volatile("s_waitcnt vmcnt(8)" ::: "memory");
        else if (tt == NT - 3) asm volatile("s_waitcnt vmcnt(4)" ::: "memory");
        else if (tt == NT - 2) asm volatile("s_waitcnt vmcnt(0)" ::: "memory");
        __builtin_amdgcn_sched_barrier(0);
        __builtin_amdgcn_s_barrier();
        asm volatile("s_waitcnt lgkmcnt(0)" ::: "memory");
        __builtin_amdgcn_sched_barrier(0);
        __builtin_amdgcn_s_setprio(1);
#pragma unroll
        for (int m = 0; m < 4; ++m)
#pragma unroll
            for (int n = 0; n < 4; ++n)
                acc[m + 4][n] = __builtin_amdgcn_mfma_f32_16x16x32_bf16(a1[m], b[n], acc[m + 4][n], 0, 0, 0);
        __builtin_amdgcn_s_setprio(0);
        __builtin_amdgcn_sched_barrier(0);
        __builtin_amdgcn_s_barrier();
    }

    // epilogue: C/D layout col=lane&15, row=(lane>>4)*4+reg
#pragma unroll
    for (int m = 0; m < 8; ++m) {
        int gr = row0 + wr * 128 + m * 16 + c16 * 4;
#pragma unroll
        for (int n = 0; n < 4; ++n) {
            int gc = col0 + wc * 64 + n * 16 + lr;
#pragma unroll
            for (int j = 0; j < 4; ++j)
                C[(size_t)(gr + j) * 1024 + gc] = f2b(acc[m][n][j]);
        }
    }
}

// ---------------- gf[b,e] = mean_n( l2norm(K_pre)[n,e] * V[n,e] ) -----------
__global__ __launch_bounds__(256) void kv_reduce(const ushort* __restrict__ Kp,
                                                 const ushort* __restrict__ Vp,
                                                 float* __restrict__ gf) {
    const int D = 1024, N = 4096;
    int b = blockIdx.y;
    int t = threadIdx.x, l = t & 63, w = t >> 6;
    int r0 = blockIdx.x * 128 + w * 32;  // gridDim.x = 32, 4 waves x 32 rows
    __shared__ float part[4][1024];

    float acc[2][8] = {};
    for (int r = 0; r < 32; ++r) {
        size_t row = (size_t)b * N + r0 + r;
        bf16x8 kv0 = *(const bf16x8*)&Kp[row * D + l * 8];
        bf16x8 kv1 = *(const bf16x8*)&Kp[row * D + l * 8 + 512];
        bf16x8 vv0 = *(const bf16x8*)&Vp[row * D + l * 8];
        bf16x8 vv1 = *(const bf16x8*)&Vp[row * D + l * 8 + 512];
        float kf0[8], kf1[8], ss = 0.f;
#pragma unroll
        for (int j = 0; j < 8; ++j) {
            kf0[j] = b2f((ushort)kv0[j]);
            kf1[j] = b2f((ushort)kv1[j]);
            ss += kf0[j] * kf0[j] + kf1[j] * kf1[j];
        }
#pragma unroll
        for (int off = 32; off; off >>= 1) ss += __shfl_xor(ss, off);
        float inv = 1.0f / fmaxf(sqrtf(ss), 1e-12f);
#pragma unroll
        for (int j = 0; j < 8; ++j) {
            acc[0][j] += kf0[j] * inv * b2f((ushort)vv0[j]);
            acc[1][j] += kf1[j] * inv * b2f((ushort)vv1[j]);
        }
    }
#pragma unroll
    for (int i = 0; i < 2; ++i)
#pragma unroll
        for (int j = 0; j < 8; ++j)
            part[w][l * 8 + i * 512 + j] = acc[i][j];
    __syncthreads();
    const float sc = 1.0f / 4096.0f;
#pragma unroll
    for (int i = 0; i < 4; ++i) {
        int c = t * 4 + i;
        float s = part[0][c] + part[1][c] + part[2][c] + part[3][c];
        atomicAdd(&gf[b * D + c], s * sc);
    }
}

// ---------------- out[row,e] = l2norm(Q_pre)[row,e] * gf[b,e]  (fp32 out) ---
__global__ __launch_bounds__(256) void q_scale(const ushort* __restrict__ Qp,
                                               const float* __restrict__ gf,
                                               float* __restrict__ out) {
    const int D = 1024;
    int row = blockIdx.x * 4 + (threadIdx.x >> 6);
    int l = threadIdx.x & 63;
    int b = row >> 12;  // N = 4096
    const ushort* qr = &Qp[(size_t)row * D];
    float qf[4][4];
    float ss = 0.f;
#pragma unroll
    for (int i = 0; i < 4; ++i) {
        ushort4 q = *(const ushort4*)&qr[l * 4 + i * 256];
        qf[i][0] = b2f(q.x); qf[i][1] = b2f(q.y);
        qf[i][2] = b2f(q.z); qf[i][3] = b2f(q.w);
        ss += qf[i][0] * qf[i][0] + qf[i][1] * qf[i][1] +
              qf[i][2] * qf[i][2] + qf[i][3] * qf[i][3];
    }
#pragma unroll
    for (int off = 32; off; off >>= 1) ss += __shfl_xor(ss, off);
    float inv = 1.0f / fmaxf(sqrtf(ss), 1e-12f);
#pragma unroll
    for (int i = 0; i < 4; ++i) {
        float4 g = *(const float4*)&gf[b * D + l * 4 + i * 256];
        float4 o;
        o.x = qf[i][0] * inv * g.x;
        o.y = qf[i][1] * inv * g.y;
        o.z = qf[i][2] * inv * g.z;
        o.w = qf[i][3] * inv * g.w;
        *(float4*)&out[(size_t)row * D + l * 4 + i * 256] = o;
    }
}

extern "C" void kernel_launch(void* const* d_in, const int* in_sizes, int n_in,
                              void* d_out, int out_size, void* d_ws, size_t ws_size,
                              hipStream_t stream) {
    const float* x  = (const float*)d_in[0];
    const float* Wq = (const float*)d_in[1];
    const float* Wk = (const float*)d_in[2];
    const float* Wv = (const float*)d_in[3];
    float* out = (float*)d_out;

    const int Bb = 8, Nn = 4096, D = 1024;
    const int M = Bb * Nn;  // 32768 rows

    char* ws = (char*)d_ws;
    ushort* xb  = (ushort*)ws;                         // 67108864 B
    ushort* wqb = (ushort*)(ws + 67108864);            // 2097152 B  } contiguous
    ushort* wkb = (ushort*)(ws + 69206016);            // 2097152 B  } bf16 W's
    ushort* wvb = (ushort*)(ws + 71303168);            // 2097152 B  }
    ushort* P1  = (ushort*)(ws + 73400320);            // 67108864 B (Q_pre)
    float*  gf  = (float*)(ws + 140509184);            // 32768 B

    // d_out (134.2 MB) doubles as bf16 scratch for K_pre / V until q_scale.
    ushort* Kp = (ushort*)d_out;
    ushort* Vp = Kp + (size_t)M * D;

    hipMemsetAsync(gf, 0, Bb * D * sizeof(float), stream);

    f2b_kernel<<<2048, 256, 0, stream>>>(x, xb, (M * D) / 4);
    f2b3_kernel<<<1536, 256, 0, stream>>>(Wq, Wk, Wv, wqb, (D * D) / 4);

    gemm_bt5<<<512, 512, 0, stream>>>(xb, wkb, Kp);
    gemm_bt5<<<512, 512, 0, stream>>>(xb, wvb, Vp);
    kv_reduce<<<dim3(32, 8), 256, 0, stream>>>(Kp, Vp, gf);
    gemm_bt5<<<512, 512, 0, stream>>>(xb, wqb, P1);
    q_scale<<<M / 4, 256, 0, stream>>>(P1, gf, out);
}

// Round 9
// 330.486 us; speedup vs baseline: 1.0918x; 1.0147x over previous
//
#include <hip/hip_runtime.h>

typedef __attribute__((ext_vector_type(4))) float f32x4;
typedef __attribute__((ext_vector_type(8))) short bf16x8;

#define AS1 __attribute__((address_space(1)))
#define AS3 __attribute__((address_space(3)))

static __device__ __forceinline__ ushort f2b(float f) {
    uint u = __float_as_uint(f);
    uint r = (u + 0x7fffu + ((u >> 16) & 1u)) >> 16;
    return (ushort)r;
}
static __device__ __forceinline__ float b2f(ushort h) {
    return __uint_as_float(((uint)h) << 16);
}

// ---------------- fp32 -> bf16 convert (vectorized, grid-stride) -------------
__global__ __launch_bounds__(256) void f2b_kernel(const float* __restrict__ in,
                                                  ushort* __restrict__ out, int n4) {
    int i = blockIdx.x * blockDim.x + threadIdx.x;
    int stride = gridDim.x * blockDim.x;
    for (; i < n4; i += stride) {
        float4 v = ((const float4*)in)[i];
        ushort4 o;
        o.x = f2b(v.x); o.y = f2b(v.y); o.z = f2b(v.z); o.w = f2b(v.w);
        ((ushort4*)out)[i] = o;
    }
}

// ---- three equally-sized fp32 arrays -> one contiguous bf16 output ---------
__global__ __launch_bounds__(256) void f2b3_kernel(const float* __restrict__ A,
                                                   const float* __restrict__ B,
                                                   const float* __restrict__ C,
                                                   ushort* __restrict__ out, int n4) {
    int i = blockIdx.x * blockDim.x + threadIdx.x;
    int stride = gridDim.x * blockDim.x;
    for (; i < 3 * n4; i += stride) {
        const float* src = (i < n4) ? A : ((i < 2 * n4) ? B : C);
        int j = (i < n4) ? i : ((i < 2 * n4) ? i - n4 : i - 2 * n4);
        float4 v = ((const float4*)src)[j];
        ushort4 o;
        o.x = f2b(v.x); o.y = f2b(v.y); o.z = f2b(v.z); o.w = f2b(v.w);
        ((ushort4*)out)[i] = o;
    }
}

// ---------------- bf16 GEMM, C = A * B^T, 256x256, BK=64, 4-phase ----------
// Quarter-tiles 64x64 (8KB = 1 global_load_lds instr per thread). LDS:
// [2 buf][4 quarter] per matrix = 128 KiB. Per K-tile: 4 phases = C-quadrants,
// reads {12,4,8,0} b128, b-frags held in regs; stage kt+1's 8 quarters at
// ph1 (B q0-3), ph2 (A q0,q2), ph3 (A q1,q3) -> >=2-phase flight;
// vmcnt(6)@ph2 gates prior A-odd, vmcnt(2)@ph4 gates B+A-even. Swizzle:
// within-row slot = (k*4+c16) ^ (l&7); staging source chunk = (l&7)^((l>>3)&7).
__device__ __forceinline__ void stage_q(const ushort* __restrict__ G,
                                        ushort* Ls, int buf, int q, int rc0,
                                        int kcol, int w, int srow, int schunk) {
    ushort* dst = Ls + (buf * 4 + q) * 4096 + w * 512;  // wave-uniform base
    const ushort* src = G + (size_t)(rc0 + q * 64 + srow) * 1024 + kcol + schunk * 8;
    __builtin_amdgcn_global_load_lds((const AS1 void*)src, (AS3 void*)dst, 16, 0, 0);
}

#define PIN_PRE()  do { __builtin_amdgcn_sched_barrier(0); \
                        __builtin_amdgcn_s_barrier(); \
                        asm volatile("s_waitcnt lgkmcnt(0)" ::: "memory"); \
                        __builtin_amdgcn_sched_barrier(0); \
                        __builtin_amdgcn_s_setprio(1); } while (0)
#define PIN_POST() do { __builtin_amdgcn_s_setprio(0); \
                        __builtin_amdgcn_sched_barrier(0); \
                        __builtin_amdgcn_s_barrier(); } while (0)

__global__ __launch_bounds__(512, 2) void gemm_bt6(const ushort* __restrict__ A,
                                                   const ushort* __restrict__ Bw,
                                                   ushort* __restrict__ C) {
    __shared__ ushort As[8 * 4096];  // 64 KiB
    __shared__ ushort Bs[8 * 4096];  // 64 KiB

    // T1: XCD-chunked swizzle (nwg = 512)
    int nwg = gridDim.x, cpx = nwg >> 3, bid = blockIdx.x;
    int orig = (bid & 7) * cpx + (bid >> 3);
    int rt = orig >> 2, ct = orig & 3;
    int row0 = rt * 256, col0 = ct * 256;

    int t = threadIdx.x, l = t & 63, w = t >> 6;
    int wr = w >> 2, wc = w & 3;     // wave grid 2 (M) x 4 (N)
    int lr = l & 15, c16 = l >> 4;

    int srow = t >> 3;                     // staging row within quarter
    int schunk = (l & 7) ^ ((l >> 3) & 7); // staging source 16B chunk
    int o0 = ((c16 ^ (l & 7))) * 16;       // read slot bytes, k=0
    int o1 = o0 ^ 64;                      // k=1

    f32x4 acc[8][4] = {};
    bf16x8 a[4][2], blo[2][2], bhi[2][2];

    const int NT = 16;  // K=1024 / 64
    // prologue: stage K-tile 0 (buf 0) fully, drain, barrier
#pragma unroll
    for (int q = 0; q < 4; ++q) stage_q(Bw, Bs, 0, q, col0, 0, w, srow, schunk);
#pragma unroll
    for (int q = 0; q < 4; ++q) stage_q(A, As, 0, q, row0, 0, w, srow, schunk);
    asm volatile("s_waitcnt vmcnt(0)" ::: "memory");
    __builtin_amdgcn_s_barrier();

    for (int kt = 0; kt < NT; ++kt) {
        int buf = kt & 1, bufn = buf ^ 1;
        int kcoln = (kt + 1) * 64;
        const char* AqL = (const char*)As + buf * 32768 + (2 * wr) * 8192 + lr * 128;
        const char* AqH = AqL + 8192;
        const char* Bq  = (const char*)Bs + buf * 32768 + wc * 8192 + lr * 128;

        // ===== P1 [mlo x nlo]: read a-lo(8) + b-lo(4); stage B q0-3(kt+1) ====
#pragma unroll
        for (int mf = 0; mf < 4; ++mf) {
            a[mf][0] = *(const bf16x8*)(AqL + mf * 2048 + o0);
            a[mf][1] = *(const bf16x8*)(AqL + mf * 2048 + o1);
        }
#pragma unroll
        for (int nf = 0; nf < 2; ++nf) {
            blo[nf][0] = *(const bf16x8*)(Bq + nf * 2048 + o0);
            blo[nf][1] = *(const bf16x8*)(Bq + nf * 2048 + o1);
        }
        if (kt + 1 < NT) {
#pragma unroll
            for (int q = 0; q < 4; ++q)
                stage_q(Bw, Bs, bufn, q, col0, kcoln, w, srow, schunk);
        }
        asm volatile("s_waitcnt lgkmcnt(8)" ::: "memory");
        PIN_PRE();
#pragma unroll
        for (int mf = 0; mf < 4; ++mf)
#pragma unroll
            for (int nf = 0; nf < 2; ++nf)
#pragma unroll
                for (int k = 0; k < 2; ++k)
                    acc[mf][nf] = __builtin_amdgcn_mfma_f32_16x16x32_bf16(a[mf][k], blo[nf][k], acc[mf][nf], 0, 0, 0);
        PIN_POST();

        // ===== P2 [mlo x nhi]: read b-hi(4); stage A q0,q2(kt+1); vmcnt =====
#pragma unroll
        for (int nf = 0; nf < 2; ++nf) {
            bhi[nf][0] = *(const bf16x8*)(Bq + (2 + nf) * 2048 + o0);
            bhi[nf][1] = *(const bf16x8*)(Bq + (2 + nf) * 2048 + o1);
        }
        if (kt + 1 < NT) {
            stage_q(A, As, bufn, 0, row0, kcoln, w, srow, schunk);
            stage_q(A, As, bufn, 2, row0, kcoln, w, srow, schunk);
        }
        if (kt == NT - 1) asm volatile("s_waitcnt vmcnt(0)" ::: "memory");
        else              asm volatile("s_waitcnt vmcnt(6)" ::: "memory");
        PIN_PRE();
#pragma unroll
        for (int mf = 0; mf < 4; ++mf)
#pragma unroll
            for (int nf = 0; nf < 2; ++nf)
#pragma unroll
                for (int k = 0; k < 2; ++k)
                    acc[mf][2 + nf] = __builtin_amdgcn_mfma_f32_16x16x32_bf16(a[mf][k], bhi[nf][k], acc[mf][2 + nf], 0, 0, 0);
        PIN_POST();

        // ===== P3 [mhi x nlo]: read a-hi(8); stage A q1,q3(kt+1) ============
#pragma unroll
        for (int mf = 0; mf < 4; ++mf) {
            a[mf][0] = *(const bf16x8*)(AqH + mf * 2048 + o0);
            a[mf][1] = *(const bf16x8*)(AqH + mf * 2048 + o1);
        }
        if (kt + 1 < NT) {
            stage_q(A, As, bufn, 1, row0, kcoln, w, srow, schunk);
            stage_q(A, As, bufn, 3, row0, kcoln, w, srow, schunk);
        }
        PIN_PRE();
#pragma unroll
        for (int mf = 0; mf < 4; ++mf)
#pragma unroll
            for (int nf = 0; nf < 2; ++nf)
#pragma unroll
                for (int k = 0; k < 2; ++k)
                    acc[4 + mf][nf] = __builtin_amdgcn_mfma_f32_16x16x32_bf16(a[mf][k], blo[nf][k], acc[4 + mf][nf], 0, 0, 0);
        PIN_POST();

        // ===== P4 [mhi x nhi]: no reads; vmcnt(2) gates B+A-even(kt+1) ======
        if (kt + 1 < NT) asm volatile("s_waitcnt vmcnt(2)" ::: "memory");
        __builtin_amdgcn_sched_barrier(0);
        __builtin_amdgcn_s_barrier();
        __builtin_amdgcn_sched_barrier(0);
        __builtin_amdgcn_s_setprio(1);
#pragma unroll
        for (int mf = 0; mf < 4; ++mf)
#pragma unroll
            for (int nf = 0; nf < 2; ++nf)
#pragma unroll
                for (int k = 0; k < 2; ++k)
                    acc[4 + mf][2 + nf] = __builtin_amdgcn_mfma_f32_16x16x32_bf16(a[mf][k], bhi[nf][k], acc[4 + mf][2 + nf], 0, 0, 0);
        PIN_POST();
    }

    // epilogue: C/D layout col=lane&15, row=(lane>>4)*4+reg
#pragma unroll
    for (int m = 0; m < 8; ++m) {
        int gr = row0 + wr * 128 + m * 16 + c16 * 4;
#pragma unroll
        for (int n = 0; n < 4; ++n) {
            int gc = col0 + wc * 64 + n * 16 + lr;
#pragma unroll
            for (int j = 0; j < 4; ++j)
                C[(size_t)(gr + j) * 1024 + gc] = f2b(acc[m][n][j]);
        }
    }
}

// ---------------- gf[b,e] = mean_n( l2norm(K_pre)[n,e] * V[n,e] ) -----------
__global__ __launch_bounds__(256) void kv_reduce(const ushort* __restrict__ Kp,
                                                 const ushort* __restrict__ Vp,
                                                 float* __restrict__ gf) {
    const int D = 1024, N = 4096;
    int b = blockIdx.y;
    int t = threadIdx.x, l = t & 63, w = t >> 6;
    int r0 = blockIdx.x * 128 + w * 32;
    __shared__ float part[4][1024];

    float acc[2][8] = {};
    for (int r = 0; r < 32; ++r) {
        size_t row = (size_t)b * N + r0 + r;
        bf16x8 kv0 = *(const bf16x8*)&Kp[row * D + l * 8];
        bf16x8 kv1 = *(const bf16x8*)&Kp[row * D + l * 8 + 512];
        bf16x8 vv0 = *(const bf16x8*)&Vp[row * D + l * 8];
        bf16x8 vv1 = *(const bf16x8*)&Vp[row * D + l * 8 + 512];
        float kf0[8], kf1[8], ss = 0.f;
#pragma unroll
        for (int j = 0; j < 8; ++j) {
            kf0[j] = b2f((ushort)kv0[j]);
            kf1[j] = b2f((ushort)kv1[j]);
            ss += kf0[j] * kf0[j] + kf1[j] * kf1[j];
        }
#pragma unroll
        for (int off = 32; off; off >>= 1) ss += __shfl_xor(ss, off);
        float inv = 1.0f / fmaxf(sqrtf(ss), 1e-12f);
#pragma unroll
        for (int j = 0; j < 8; ++j) {
            acc[0][j] += kf0[j] * inv * b2f((ushort)vv0[j]);
            acc[1][j] += kf1[j] * inv * b2f((ushort)vv1[j]);
        }
    }
#pragma unroll
    for (int i = 0; i < 2; ++i)
#pragma unroll
        for (int j = 0; j < 8; ++j)
            part[w][l * 8 + i * 512 + j] = acc[i][j];
    __syncthreads();
    const float sc = 1.0f / 4096.0f;
#pragma unroll
    for (int i = 0; i < 4; ++i) {
        int c = t * 4 + i;
        float s = part[0][c] + part[1][c] + part[2][c] + part[3][c];
        atomicAdd(&gf[b * D + c], s * sc);
    }
}

// ---------------- out[row,e] = l2norm(Q_pre)[row,e] * gf[b,e]  (fp32 out) ---
__global__ __launch_bounds__(256) void q_scale(const ushort* __restrict__ Qp,
                                               const float* __restrict__ gf,
                                               float* __restrict__ out) {
    const int D = 1024;
    int row = blockIdx.x * 4 + (threadIdx.x >> 6);
    int l = threadIdx.x & 63;
    int b = row >> 12;
    const ushort* qr = &Qp[(size_t)row * D];
    float qf[4][4];
    float ss = 0.f;
#pragma unroll
    for (int i = 0; i < 4; ++i) {
        ushort4 q = *(const ushort4*)&qr[l * 4 + i * 256];
        qf[i][0] = b2f(q.x); qf[i][1] = b2f(q.y);
        qf[i][2] = b2f(q.z); qf[i][3] = b2f(q.w);
        ss += qf[i][0] * qf[i][0] + qf[i][1] * qf[i][1] +
              qf[i][2] * qf[i][2] + qf[i][3] * qf[i][3];
    }
#pragma unroll
    for (int off = 32; off; off >>= 1) ss += __shfl_xor(ss, off);
    float inv = 1.0f / fmaxf(sqrtf(ss), 1e-12f);
#pragma unroll
    for (int i = 0; i < 4; ++i) {
        float4 g = *(const float4*)&gf[b * D + l * 4 + i * 256];
        float4 o;
        o.x = qf[i][0] * inv * g.x;
        o.y = qf[i][1] * inv * g.y;
        o.z = qf[i][2] * inv * g.z;
        o.w = qf[i][3] * inv * g.w;
        *(float4*)&out[(size_t)row * D + l * 4 + i * 256] = o;
    }
}

extern "C" void kernel_launch(void* const* d_in, const int* in_sizes, int n_in,
                              void* d_out, int out_size, void* d_ws, size_t ws_size,
                              hipStream_t stream) {
    const float* x  = (const float*)d_in[0];
    const float* Wq = (const float*)d_in[1];
    const float* Wk = (const float*)d_in[2];
    const float* Wv = (const float*)d_in[3];
    float* out = (float*)d_out;

    const int Bb = 8, Nn = 4096, D = 1024;
    const int M = Bb * Nn;  // 32768 rows

    char* ws = (char*)d_ws;
    ushort* xb  = (ushort*)ws;                         // 67108864 B
    ushort* wqb = (ushort*)(ws + 67108864);            // 2097152 B  } contiguous
    ushort* wkb = (ushort*)(ws + 69206016);            // 2097152 B  } bf16 W's
    ushort* wvb = (ushort*)(ws + 71303168);            // 2097152 B  }
    ushort* P1  = (ushort*)(ws + 73400320);            // 67108864 B (Q_pre)
    float*  gf  = (float*)(ws + 140509184);            // 32768 B

    // d_out (134.2 MB) doubles as bf16 scratch for K_pre / V until q_scale.
    ushort* Kp = (ushort*)d_out;
    ushort* Vp = Kp + (size_t)M * D;

    hipMemsetAsync(gf, 0, Bb * D * sizeof(float), stream);

    f2b_kernel<<<2048, 256, 0, stream>>>(x, xb, (M * D) / 4);
    f2b3_kernel<<<1536, 256, 0, stream>>>(Wq, Wk, Wv, wqb, (D * D) / 4);

    gemm_bt6<<<512, 512, 0, stream>>>(xb, wkb, Kp);
    gemm_bt6<<<512, 512, 0, stream>>>(xb, wvb, Vp);
    kv_reduce<<<dim3(32, 8), 256, 0, stream>>>(Kp, Vp, gf);
    gemm_bt6<<<512, 512, 0, stream>>>(xb, wqb, P1);
    q_scale<<<M / 4, 256, 0, stream>>>(P1, gf, out);
}

// Round 10
// 302.355 us; speedup vs baseline: 1.1933x; 1.0930x over previous
//
#include <hip/hip_runtime.h>

typedef __attribute__((ext_vector_type(4))) float f32x4;
typedef __attribute__((ext_vector_type(8))) short bf16x8;

#define AS1 __attribute__((address_space(1)))
#define AS3 __attribute__((address_space(3)))

static __device__ __forceinline__ ushort f2b(float f) {
    uint u = __float_as_uint(f);
    uint r = (u + 0x7fffu + ((u >> 16) & 1u)) >> 16;
    return (ushort)r;
}
static __device__ __forceinline__ float b2f(ushort h) {
    return __uint_as_float(((uint)h) << 16);
}

// ---------------- fp32 -> bf16 convert (vectorized, grid-stride) -------------
__global__ __launch_bounds__(256) void f2b_kernel(const float* __restrict__ in,
                                                  ushort* __restrict__ out, int n4) {
    int i = blockIdx.x * blockDim.x + threadIdx.x;
    int stride = gridDim.x * blockDim.x;
    for (; i < n4; i += stride) {
        float4 v = ((const float4*)in)[i];
        ushort4 o;
        o.x = f2b(v.x); o.y = f2b(v.y); o.z = f2b(v.z); o.w = f2b(v.w);
        ((ushort4*)out)[i] = o;
    }
}

// ---- three equally-sized fp32 arrays -> one contiguous bf16 output ---------
__global__ __launch_bounds__(256) void f2b3_kernel(const float* __restrict__ A,
                                                   const float* __restrict__ B,
                                                   const float* __restrict__ C,
                                                   ushort* __restrict__ out, int n4) {
    int i = blockIdx.x * blockDim.x + threadIdx.x;
    int stride = gridDim.x * blockDim.x;
    for (; i < 3 * n4; i += stride) {
        const float* src = (i < n4) ? A : ((i < 2 * n4) ? B : C);
        int j = (i < n4) ? i : ((i < 2 * n4) ? i - n4 : i - 2 * n4);
        float4 v = ((const float4*)src)[j];
        ushort4 o;
        o.x = f2b(v.x); o.y = f2b(v.y); o.z = f2b(v.z); o.w = f2b(v.w);
        ((ushort4*)out)[i] = o;
    }
}

// ---------------- bf16 GEMM, C = A * B^T, 256x256, BK=64, 4-phase ----------
// Quarter-tiles 64x64 (8KB = 1 global_load_lds per thread). Deep staging:
// during kt -> P1: A-odd(kt+1); P2: A-even(kt+2); P3: B01(kt+2); P4: B23(kt+2).
// ONE vmcnt(6) checkpoint at P4 seals exactly buf(kt+1) (all loads >=3 phases
// old). Every staged quarter's slot had its last read >=1 barrier before the
// stage issue (A-even read@P1, B@P1/P2, A-odd@P3 of the prior tile) -> safe.
// Epilogue: C tile staged through LDS (reuses the 128KB), 16B coalesced stores.
__device__ __forceinline__ void stage_q(const ushort* __restrict__ G,
                                        ushort* Ls, int buf, int q, int rc0,
                                        int kcol, int w, int srow, int schunk) {
    ushort* dst = Ls + (buf * 4 + q) * 4096 + w * 512;  // wave-uniform base
    const ushort* src = G + (size_t)(rc0 + q * 64 + srow) * 1024 + kcol + schunk * 8;
    __builtin_amdgcn_global_load_lds((const AS1 void*)src, (AS3 void*)dst, 16, 0, 0);
}

#define PIN_PRE()  do { __builtin_amdgcn_sched_barrier(0); \
                        __builtin_amdgcn_s_barrier(); \
                        asm volatile("s_waitcnt lgkmcnt(0)" ::: "memory"); \
                        __builtin_amdgcn_sched_barrier(0); \
                        __builtin_amdgcn_s_setprio(1); } while (0)
#define PIN_POST() do { __builtin_amdgcn_s_setprio(0); \
                        __builtin_amdgcn_sched_barrier(0); \
                        __builtin_amdgcn_s_barrier(); } while (0)

__global__ __launch_bounds__(512, 2) void gemm_bt7(const ushort* __restrict__ A,
                                                   const ushort* __restrict__ Bw,
                                                   ushort* __restrict__ C) {
    __shared__ ushort SMEM[65536];   // 128 KiB: As | Bs, reused for C epilogue
    ushort* As = SMEM;
    ushort* Bs = SMEM + 32768;

    // T1: XCD-chunked swizzle (nwg = 512)
    int nwg = gridDim.x, cpx = nwg >> 3, bid = blockIdx.x;
    int orig = (bid & 7) * cpx + (bid >> 3);
    int rt = orig >> 2, ct = orig & 3;
    int row0 = rt * 256, col0 = ct * 256;

    int t = threadIdx.x, l = t & 63, w = t >> 6;
    int wr = w >> 2, wc = w & 3;     // wave grid 2 (M) x 4 (N)
    int lr = l & 15, c16 = l >> 4;

    int srow = t >> 3;                     // staging row within quarter
    int schunk = (l & 7) ^ ((l >> 3) & 7); // staging source 16B chunk
    int o0 = ((c16 ^ (l & 7))) * 16;       // read slot bytes, k=0
    int o1 = o0 ^ 64;                      // k=1

    f32x4 acc[8][4] = {};
    bf16x8 a[4], blo[2][2], bhi[2][2];

    const int NT = 16;  // K=1024 / 64
    // prologue: buf0 all 8 quarters; buf1 first 6 (A q0,q2 + B q0-3)
#pragma unroll
    for (int q = 0; q < 4; ++q) stage_q(Bw, Bs, 0, q, col0, 0, w, srow, schunk);
#pragma unroll
    for (int q = 0; q < 4; ++q) stage_q(A, As, 0, q, row0, 0, w, srow, schunk);
    stage_q(A, As, 1, 0, row0, 64, w, srow, schunk);
    stage_q(A, As, 1, 2, row0, 64, w, srow, schunk);
#pragma unroll
    for (int q = 0; q < 4; ++q) stage_q(Bw, Bs, 1, q, col0, 64, w, srow, schunk);
    asm volatile("s_waitcnt vmcnt(6)" ::: "memory");  // seals buf0 (8 oldest)
    __builtin_amdgcn_s_barrier();

    for (int kt = 0; kt < NT; ++kt) {
        int buf = kt & 1, bn = buf ^ 1;
        int kc1 = (kt + 1) * 64, kc2 = (kt + 2) * 64;
        const char* AqL = (const char*)As + buf * 32768 + (2 * wr) * 8192 + lr * 128;
        const char* AqH = AqL + 8192;
        const char* Bq  = (const char*)Bs + buf * 32768 + wc * 8192 + lr * 128;
        bf16x8 a2[4];

        // ===== P1 [mlo x nlo]: read a-lo(8) + b-lo(4); stage A-odd(kt+1) ====
#pragma unroll
        for (int mf = 0; mf < 4; ++mf) {
            a[mf]  = *(const bf16x8*)(AqL + mf * 2048 + o0);
            a2[mf] = *(const bf16x8*)(AqL + mf * 2048 + o1);
        }
#pragma unroll
        for (int nf = 0; nf < 2; ++nf) {
            blo[nf][0] = *(const bf16x8*)(Bq + nf * 2048 + o0);
            blo[nf][1] = *(const bf16x8*)(Bq + nf * 2048 + o1);
        }
        if (kt + 1 < NT) {
            stage_q(A, As, bn, 1, row0, kc1, w, srow, schunk);
            stage_q(A, As, bn, 3, row0, kc1, w, srow, schunk);
        }
        asm volatile("s_waitcnt lgkmcnt(8)" ::: "memory");
        PIN_PRE();
#pragma unroll
        for (int mf = 0; mf < 4; ++mf)
#pragma unroll
            for (int nf = 0; nf < 2; ++nf) {
                acc[mf][nf] = __builtin_amdgcn_mfma_f32_16x16x32_bf16(a[mf],  blo[nf][0], acc[mf][nf], 0, 0, 0);
                acc[mf][nf] = __builtin_amdgcn_mfma_f32_16x16x32_bf16(a2[mf], blo[nf][1], acc[mf][nf], 0, 0, 0);
            }
        PIN_POST();

        // ===== P2 [mlo x nhi]: read b-hi(4); stage A-even(kt+2) =============
#pragma unroll
        for (int nf = 0; nf < 2; ++nf) {
            bhi[nf][0] = *(const bf16x8*)(Bq + (2 + nf) * 2048 + o0);
            bhi[nf][1] = *(const bf16x8*)(Bq + (2 + nf) * 2048 + o1);
        }
        if (kt + 2 < NT) {
            stage_q(A, As, buf, 0, row0, kc2, w, srow, schunk);
            stage_q(A, As, buf, 2, row0, kc2, w, srow, schunk);
        }
        PIN_PRE();
#pragma unroll
        for (int mf = 0; mf < 4; ++mf)
#pragma unroll
            for (int nf = 0; nf < 2; ++nf) {
                acc[mf][2 + nf] = __builtin_amdgcn_mfma_f32_16x16x32_bf16(a[mf],  bhi[nf][0], acc[mf][2 + nf], 0, 0, 0);
                acc[mf][2 + nf] = __builtin_amdgcn_mfma_f32_16x16x32_bf16(a2[mf], bhi[nf][1], acc[mf][2 + nf], 0, 0, 0);
            }
        PIN_POST();

        // ===== P3 [mhi x nlo]: read a-hi(8); stage B q0,q1(kt+2) ============
#pragma unroll
        for (int mf = 0; mf < 4; ++mf) {
            a[mf]  = *(const bf16x8*)(AqH + mf * 2048 + o0);
            a2[mf] = *(const bf16x8*)(AqH + mf * 2048 + o1);
        }
        if (kt + 2 < NT) {
            stage_q(Bw, Bs, buf, 0, col0, kc2, w, srow, schunk);
            stage_q(Bw, Bs, buf, 1, col0, kc2, w, srow, schunk);
        }
        PIN_PRE();
#pragma unroll
        for (int mf = 0; mf < 4; ++mf)
#pragma unroll
            for (int nf = 0; nf < 2; ++nf) {
                acc[4 + mf][nf] = __builtin_amdgcn_mfma_f32_16x16x32_bf16(a[mf],  blo[nf][0], acc[4 + mf][nf], 0, 0, 0);
                acc[4 + mf][nf] = __builtin_amdgcn_mfma_f32_16x16x32_bf16(a2[mf], blo[nf][1], acc[4 + mf][nf], 0, 0, 0);
            }
        PIN_POST();

        // ===== P4 [mhi x nhi]: stage B q2,q3(kt+2); ONE vmcnt checkpoint ====
        if (kt + 2 < NT) {
            stage_q(Bw, Bs, buf, 2, col0, kc2, w, srow, schunk);
            stage_q(Bw, Bs, buf, 3, col0, kc2, w, srow, schunk);
        }
        if (kt + 2 < NT)      asm volatile("s_waitcnt vmcnt(6)" ::: "memory");
        else if (kt + 1 < NT) asm volatile("s_waitcnt vmcnt(0)" ::: "memory");
        __builtin_amdgcn_sched_barrier(0);
        __builtin_amdgcn_s_barrier();
        __builtin_amdgcn_sched_barrier(0);
        __builtin_amdgcn_s_setprio(1);
#pragma unroll
        for (int mf = 0; mf < 4; ++mf)
#pragma unroll
            for (int nf = 0; nf < 2; ++nf) {
                acc[4 + mf][2 + nf] = __builtin_amdgcn_mfma_f32_16x16x32_bf16(a[mf],  bhi[nf][0], acc[4 + mf][2 + nf], 0, 0, 0);
                acc[4 + mf][2 + nf] = __builtin_amdgcn_mfma_f32_16x16x32_bf16(a2[mf], bhi[nf][1], acc[4 + mf][2 + nf], 0, 0, 0);
            }
        PIN_POST();
    }

    // ---- epilogue via LDS: scalar ds_writes, coalesced 16B global stores ----
    // (K-loop's final barrier has passed; SMEM free to reuse.)
#pragma unroll
    for (int m = 0; m < 8; ++m) {
        int lrow = wr * 128 + m * 16 + c16 * 4;
#pragma unroll
        for (int n = 0; n < 4; ++n) {
            int lcol = wc * 64 + n * 16 + lr;
#pragma unroll
            for (int j = 0; j < 4; ++j)
                SMEM[(lrow + j) * 256 + lcol] = f2b(acc[m][n][j]);
        }
    }
    __syncthreads();
#pragma unroll
    for (int g = 0; g < 16; ++g) {
        int ch = g * 512 + t;           // 16B-chunk index in the 256x256 tile
        int r = ch >> 5, c8 = ch & 31;
        bf16x8 v = *(const bf16x8*)&SMEM[ch * 8];
        *(bf16x8*)&C[(size_t)(row0 + r) * 1024 + col0 + c8 * 8] = v;
    }
}

// ---------------- gf[b,e] = mean_n( l2norm(K_pre)[n,e] * V[n,e] ) -----------
__global__ __launch_bounds__(256) void kv_reduce(const ushort* __restrict__ Kp,
                                                 const ushort* __restrict__ Vp,
                                                 float* __restrict__ gf) {
    const int D = 1024, N = 4096;
    int b = blockIdx.y;
    int t = threadIdx.x, l = t & 63, w = t >> 6;
    int r0 = blockIdx.x * 128 + w * 32;
    __shared__ float part[4][1024];

    float acc[2][8] = {};
    for (int r = 0; r < 32; ++r) {
        size_t row = (size_t)b * N + r0 + r;
        bf16x8 kv0 = *(const bf16x8*)&Kp[row * D + l * 8];
        bf16x8 kv1 = *(const bf16x8*)&Kp[row * D + l * 8 + 512];
        bf16x8 vv0 = *(const bf16x8*)&Vp[row * D + l * 8];
        bf16x8 vv1 = *(const bf16x8*)&Vp[row * D + l * 8 + 512];
        float kf0[8], kf1[8], ss = 0.f;
#pragma unroll
        for (int j = 0; j < 8; ++j) {
            kf0[j] = b2f((ushort)kv0[j]);
            kf1[j] = b2f((ushort)kv1[j]);
            ss += kf0[j] * kf0[j] + kf1[j] * kf1[j];
        }
#pragma unroll
        for (int off = 32; off; off >>= 1) ss += __shfl_xor(ss, off);
        float inv = 1.0f / fmaxf(sqrtf(ss), 1e-12f);
#pragma unroll
        for (int j = 0; j < 8; ++j) {
            acc[0][j] += kf0[j] * inv * b2f((ushort)vv0[j]);
            acc[1][j] += kf1[j] * inv * b2f((ushort)vv1[j]);
        }
    }
#pragma unroll
    for (int i = 0; i < 2; ++i)
#pragma unroll
        for (int j = 0; j < 8; ++j)
            part[w][l * 8 + i * 512 + j] = acc[i][j];
    __syncthreads();
    const float sc = 1.0f / 4096.0f;
#pragma unroll
    for (int i = 0; i < 4; ++i) {
        int c = t * 4 + i;
        float s = part[0][c] + part[1][c] + part[2][c] + part[3][c];
        atomicAdd(&gf[b * D + c], s * sc);
    }
}

// ---------------- out[row,e] = l2norm(Q_pre)[row,e] * gf[b,e]  (fp32 out) ---
__global__ __launch_bounds__(256) void q_scale(const ushort* __restrict__ Qp,
                                               const float* __restrict__ gf,
                                               float* __restrict__ out) {
    const int D = 1024;
    int row = blockIdx.x * 4 + (threadIdx.x >> 6);
    int l = threadIdx.x & 63;
    int b = row >> 12;
    const ushort* qr = &Qp[(size_t)row * D];
    float qf[4][4];
    float ss = 0.f;
#pragma unroll
    for (int i = 0; i < 4; ++i) {
        ushort4 q = *(const ushort4*)&qr[l * 4 + i * 256];
        qf[i][0] = b2f(q.x); qf[i][1] = b2f(q.y);
        qf[i][2] = b2f(q.z); qf[i][3] = b2f(q.w);
        ss += qf[i][0] * qf[i][0] + qf[i][1] * qf[i][1] +
              qf[i][2] * qf[i][2] + qf[i][3] * qf[i][3];
    }
#pragma unroll
    for (int off = 32; off; off >>= 1) ss += __shfl_xor(ss, off);
    float inv = 1.0f / fmaxf(sqrtf(ss), 1e-12f);
#pragma unroll
    for (int i = 0; i < 4; ++i) {
        float4 g = *(const float4*)&gf[b * D + l * 4 + i * 256];
        float4 o;
        o.x = qf[i][0] * inv * g.x;
        o.y = qf[i][1] * inv * g.y;
        o.z = qf[i][2] * inv * g.z;
        o.w = qf[i][3] * inv * g.w;
        *(float4*)&out[(size_t)row * D + l * 4 + i * 256] = o;
    }
}

extern "C" void kernel_launch(void* const* d_in, const int* in_sizes, int n_in,
                              void* d_out, int out_size, void* d_ws, size_t ws_size,
                              hipStream_t stream) {
    const float* x  = (const float*)d_in[0];
    const float* Wq = (const float*)d_in[1];
    const float* Wk = (const float*)d_in[2];
    const float* Wv = (const float*)d_in[3];
    float* out = (float*)d_out;

    const int Bb = 8, Nn = 4096, D = 1024;
    const int M = Bb * Nn;  // 32768 rows

    char* ws = (char*)d_ws;
    ushort* xb  = (ushort*)ws;                         // 67108864 B
    ushort* wqb = (ushort*)(ws + 67108864);            // 2097152 B  } contiguous
    ushort* wkb = (ushort*)(ws + 69206016);            // 2097152 B  } bf16 W's
    ushort* wvb = (ushort*)(ws + 71303168);            // 2097152 B  }
    ushort* P1  = (ushort*)(ws + 73400320);            // 67108864 B (Q_pre)
    float*  gf  = (float*)(ws + 140509184);            // 32768 B

    // d_out (134.2 MB) doubles as bf16 scratch for K_pre / V until q_scale.
    ushort* Kp = (ushort*)d_out;
    ushort* Vp = Kp + (size_t)M * D;

    hipMemsetAsync(gf, 0, Bb * D * sizeof(float), stream);

    f2b_kernel<<<2048, 256, 0, stream>>>(x, xb, (M * D) / 4);
    f2b3_kernel<<<1536, 256, 0, stream>>>(Wq, Wk, Wv, wqb, (D * D) / 4);

    gemm_bt7<<<512, 512, 0, stream>>>(xb, wkb, Kp);
    gemm_bt7<<<512, 512, 0, stream>>>(xb, wvb, Vp);
    kv_reduce<<<dim3(32, 8), 256, 0, stream>>>(Kp, Vp, gf);
    gemm_bt7<<<512, 512, 0, stream>>>(xb, wqb, P1);
    q_scale<<<M / 4, 256, 0, stream>>>(P1, gf, out);
}